// Round 11
// baseline (1950.629 us; speedup 1.0000x reference)
//
#include <hip/hip_runtime.h>

typedef __attribute__((ext_vector_type(8))) short bf16x8;
typedef __attribute__((ext_vector_type(4))) float f32x4;
typedef __attribute__((ext_vector_type(4))) int   i32x4;

#define DEV static __device__ __forceinline__

constexpr int BATCH = 512;
constexpr int TENC  = 64;
constexpr int DIN   = 512;
constexpr int HDIM  = 512;
constexpr int NCLS  = 38;
constexpr int STEPS = 26;
constexpr int NG    = 4 * HDIM;   // 2048

// ---- workspace layout (bytes) ----
constexpr size_t HP_OFF   = 0;                                   // bf16 [B*T][512]  H_proj
constexpr size_t HP_SZ    = (size_t)BATCH * TENC * HDIM * 2;
constexpr size_t ENC_OFF  = HP_OFF + HP_SZ;                      // bf16 [B*T][512]  encoder
constexpr size_t ENC_SZ   = (size_t)BATCH * TENC * DIN * 2;
constexpr size_t A2_OFF   = ENC_OFF + ENC_SZ;                    // bf16 [2][B][1024] ping-pong [ctx | h]
constexpr size_t A2_SZ    = (size_t)2 * BATCH * 1024 * 2;
constexpr size_t B2R_OFF  = A2_OFF + A2_SZ;                      // bf16 [2048][1024] gate-interleaved (RO)
constexpr size_t B2R_SZ   = (size_t)NG * 1024 * 2;
constexpr size_t WI2H_OFF = B2R_OFF + B2R_SZ;                    // bf16 [512][512] (RO)
constexpr size_t WI2H_SZ  = (size_t)HDIM * DIN * 2;
constexpr size_t B3_OFF   = WI2H_OFF + WI2H_SZ;                  // bf16 [576][512]  [w_h2h ; w_gen ; pad] (RO)
constexpr size_t B3_SZ    = (size_t)576 * HDIM * 2;
constexpr size_t WOH_OFF  = B3_OFF + B3_SZ;                      // f32 [2048][38] (RO)
constexpr size_t WOH_SZ   = (size_t)NG * NCLS * 4;
constexpr size_t BIAS_OFF = WOH_OFF + WOH_SZ;                    // f32 [2048] (RO)
constexpr size_t BIAS_SZ  = (size_t)NG * 4;
constexpr size_t HSEQ_OFF = BIAS_OFF + BIAS_SZ;                  // bf16 [S][B][512] (read post-decode only)
constexpr size_t HSEQ_SZ  = (size_t)STEPS * BATCH * HDIM * 2;
constexpr size_t BAR_OFF  = HSEQ_OFF + HSEQ_SZ;                  // u32 barrier state
constexpr size_t BAR_SZ   = 16384;

DEV float bf2f(unsigned short s) {
    unsigned u = ((unsigned)s) << 16;
    return __builtin_bit_cast(float, u);
}
DEV unsigned short f2bf(float f) {
    unsigned u = __builtin_bit_cast(unsigned, f);
    u = (u + 0x7fffu + ((u >> 16) & 1u)) >> 16;   // RNE
    return (unsigned short)u;
}
DEV float sigmoid_f(float x) { return 1.f / (1.f + __expf(-x)); }
DEV float tanh_f(float x) {
    x = fminf(fmaxf(x, -15.f), 15.f);
    float e = __expf(2.f * x);
    return (e - 1.f) / (e + 1.f);
}

DEV unsigned aload(const unsigned* p) {
    return __hip_atomic_load(p, __ATOMIC_RELAXED, __HIP_MEMORY_SCOPE_AGENT);
}
DEV unsigned long long aload64(const unsigned long long* p) {
    return __hip_atomic_load(p, __ATOMIC_RELAXED, __HIP_MEMORY_SCOPE_AGENT);
}
DEV void astore(unsigned* p, unsigned v) {
    __hip_atomic_store(p, v, __ATOMIC_RELAXED, __HIP_MEMORY_SCOPE_AGENT);
}
DEV bf16x8 mk_frag(unsigned long long lo, unsigned long long hi) {
    union { unsigned long long q[2]; bf16x8 v; } u;
    u.q[0] = lo; u.q[1] = hi;
    return u.v;
}

// ---------- monotonic grid barrier with throttled poll (256 blocks: 32 x 8) ----------
// Counters only increment (gen g: sub target g*8-1, root target g*32-1) -> no
// reset stores / no vmcnt on the critical path. Pollers throttle with s_sleep(1)
// (round-8 vs round-10 A/B: un-throttled polling saturates the MALL and slows
// the flip propagation; sleep-throttled was 1303us vs 1534us busy-poll).
DEV void gbar(unsigned* bar, int bid, unsigned g) {
    __syncthreads();                 // drains this block's stores (vmcnt 0)
    if (threadIdx.x == 0) {
        const int sg = bid & 31;
        unsigned* sub  = bar + sg * 32;
        unsigned* root = bar + 1024;
        unsigned* genp = bar + 1056 + sg * 32;
        bool flipped = false;
        if (__hip_atomic_fetch_add(sub, 1u, __ATOMIC_RELAXED, __HIP_MEMORY_SCOPE_AGENT) == g * 8u - 1u) {
            if (__hip_atomic_fetch_add(root, 1u, __ATOMIC_RELAXED, __HIP_MEMORY_SCOPE_AGENT) == g * 32u - 1u) {
                #pragma unroll
                for (int i = 0; i < 32; i++) astore(bar + 1056 + i * 32, g);
                flipped = true;
            }
        }
        if (!flipped) {
            while (aload(genp) < g) __builtin_amdgcn_s_sleep(1);
        }
    }
    __syncthreads();
}

// ---------------- conversion / init kernels ----------------
__global__ void conv_bf16_kernel(const float* __restrict__ in,
                                 unsigned short* __restrict__ out, int n4) {
    int i = blockIdx.x * blockDim.x + threadIdx.x;
    int stride = gridDim.x * blockDim.x;
    for (; i < n4; i += stride) {
        float4 v = ((const float4*)in)[i];
        ushort4 o;
        o.x = f2bf(v.x); o.y = f2bf(v.y); o.z = f2bf(v.z); o.w = f2bf(v.w);
        ((ushort4*)out)[i] = o;
    }
}

__global__ void build_b2r_kernel(const float* __restrict__ w_ih, const float* __restrict__ w_hh,
                                 const float* __restrict__ b_ih, const float* __restrict__ b_hh,
                                 unsigned short* __restrict__ B2r, float* __restrict__ woh,
                                 float* __restrict__ bias2r) {
    int np = blockIdx.x;            // 0..2047 (n' = u*4+g)
    int u = np >> 2, g = np & 3;
    int src = g * 512 + u;
    for (int k = threadIdx.x; k < 512; k += blockDim.x) {
        B2r[np * 1024 + k]       = f2bf(w_ih[src * 550 + k]);
        B2r[np * 1024 + 512 + k] = f2bf(w_hh[src * 512 + k]);
    }
    if (threadIdx.x < NCLS) woh[np * NCLS + threadIdx.x] = w_ih[src * 550 + 512 + threadIdx.x];
    if (threadIdx.x == 0)   bias2r[np] = b_ih[src] + b_hh[src];
}

__global__ void build_b3_kernel(const float* __restrict__ w_h2h, const float* __restrict__ w_gen,
                                unsigned short* __restrict__ B3) {
    int n = blockIdx.x;             // 0..575
    for (int k = threadIdx.x; k < 512; k += blockDim.x) {
        float v = 0.f;
        if (n < 512)      v = w_h2h[n * 512 + k];
        else if (n < 550) v = w_gen[(n - 512) * 512 + k];
        B3[n * 512 + k] = f2bf(v);
    }
}

__global__ void init_state_kernel(unsigned short* __restrict__ A2,
                                  unsigned* __restrict__ bar) {
    int b = blockIdx.x;
    for (int j = threadIdx.x; j < 512; j += blockDim.x)
        A2[b * 1024 + 512 + j] = 0;            // h part of buffer 0 = 0
    if (b == 0)
        for (int j = threadIdx.x; j < 2112; j += blockDim.x) bar[j] = 0;
}

// ---------------- generic MFMA GEMM core (used by H_proj / probs) ----------------
template<int BM, int BN, int WN, int FRM, int FRN>
DEV void gemm_core(const unsigned short* __restrict__ A, int ldA,
                   const unsigned short* __restrict__ Bm, int ldB, int K,
                   int m0, int n0, unsigned short* __restrict__ lA,
                   unsigned short* __restrict__ lB, f32x4 acc[FRM][FRN]) {
    constexpr int LSTR = 40;
    const int tid  = threadIdx.x;
    const int lane = tid & 63;
    const int wid  = tid >> 6;
    const int wm = wid / WN, wn = wid % WN;
    const int fr_row = lane & 15;
    const int fr_kb  = (lane >> 4) * 8;

    for (int k0 = 0; k0 < K; k0 += 32) {
        for (int u = tid; u < BM * 4; u += 256) {
            int r = u >> 2, cb = u & 3;
            *(i32x4*)(lA + r * LSTR + cb * 8) =
                *(const i32x4*)(A + (size_t)(m0 + r) * ldA + k0 + cb * 8);
        }
        for (int u = tid; u < BN * 4; u += 256) {
            int r = u >> 2, cb = u & 3;
            *(i32x4*)(lB + r * LSTR + cb * 8) =
                *(const i32x4*)(Bm + (size_t)(n0 + r) * ldB + k0 + cb * 8);
        }
        __syncthreads();
        bf16x8 af[FRM], bfv[FRN];
        #pragma unroll
        for (int i = 0; i < FRM; i++)
            af[i] = *(const bf16x8*)(lA + (wm * FRM * 16 + i * 16 + fr_row) * LSTR + fr_kb);
        #pragma unroll
        for (int j = 0; j < FRN; j++)
            bfv[j] = *(const bf16x8*)(lB + (wn * FRN * 16 + j * 16 + fr_row) * LSTR + fr_kb);
        #pragma unroll
        for (int i = 0; i < FRM; i++)
            #pragma unroll
            for (int j = 0; j < FRN; j++)
                acc[i][j] = __builtin_amdgcn_mfma_f32_16x16x32_bf16(af[i], bfv[j], acc[i][j], 0, 0, 0);
        __syncthreads();
    }
}

// ---------------- H_proj GEMM (bf16 output) ----------------
__global__ __launch_bounds__(256) void gemm_bf16out_kernel(
    const unsigned short* __restrict__ A, int ldA,
    const unsigned short* __restrict__ Bm, int ldB,
    unsigned short* __restrict__ C, int ldC, int K) {
    constexpr int BM = 128, BN = 128, FRM = 4, FRN = 4;
    __shared__ __align__(16) unsigned short lA[BM * 40], lB[BN * 40];
    int m0 = blockIdx.x * BM, n0 = blockIdx.y * BN;
    f32x4 acc[FRM][FRN] = {};
    gemm_core<BM, BN, 2, FRM, FRN>(A, ldA, Bm, ldB, K, m0, n0, lA, lB, acc);
    const int lane = threadIdx.x & 63, wid = threadIdx.x >> 6;
    const int wm = wid >> 1, wn = wid & 1;
    #pragma unroll
    for (int i = 0; i < FRM; i++)
        #pragma unroll
        for (int j = 0; j < FRN; j++)
            #pragma unroll
            for (int r = 0; r < 4; r++) {
                int m = m0 + wm * FRM * 16 + i * 16 + (lane >> 4) * 4 + r;
                int n = n0 + wn * FRN * 16 + j * 16 + (lane & 15);
                C[(size_t)m * ldC + n] = f2bf(acc[i][j][r]);
            }
}

// ---------------- final probs GEMM ----------------
__global__ __launch_bounds__(256) void probs_kernel(
    const unsigned short* __restrict__ hseq,   // [S*B][512] bf16
    const unsigned short* __restrict__ Bg,     // [64][512]  bf16 (w_gen padded)
    const float* __restrict__ b_gen, float* __restrict__ out) {
    __shared__ __align__(16) unsigned short lA[64 * 40], lB[64 * 40];
    int m0 = blockIdx.x * 64;
    f32x4 acc[2][2] = {};
    gemm_core<64, 64, 2, 2, 2>(hseq, 512, Bg, 512, 512, m0, 0, lA, lB, acc);
    const int lane = threadIdx.x & 63, wid = threadIdx.x >> 6;
    const int wm = wid >> 1, wn = wid & 1;
    #pragma unroll
    for (int i = 0; i < 2; i++)
        #pragma unroll
        for (int j = 0; j < 2; j++)
            #pragma unroll
            for (int r = 0; r < 4; r++) {
                int m = m0 + wm * 32 + i * 16 + (lane >> 4) * 4 + r;
                int n = wn * 32 + j * 16 + (lane & 15);
                if (n < NCLS) {
                    int ss = m >> 9, b = m & 511;   // hseq row = s*512 + b
                    out[((size_t)b * STEPS + ss) * NCLS + n] = acc[i][j][r] + b_gen[n];
                }
            }
}

// ---------------- cooperative decode: 256 blocks x 512 threads, 2 barriers/step ----------------
// Phase A (per block, its 2 batch rows): hp = h@w_h2h^T + b (local GEMV, w_h2h
// streamed from L2, hp kept in LDS) -> attention -> ctx store. Also overlaps the
// gates h-half MFMA (depends only on h(s-1)). Phase B: gates ctx-half + LSTM.
// hp32 global buffer and the phase-3 GEMM + its barrier are GONE.
__global__ __launch_bounds__(512, 2) void decode_kernel(
    const unsigned short* __restrict__ Hp,
    const unsigned short* __restrict__ enc,
    unsigned short* __restrict__ A2,       // [2][B][1024]
    const unsigned short* __restrict__ B2r,
    const float* __restrict__ bias2r,
    const float* __restrict__ woh,
    const unsigned short* __restrict__ B3, // rows 0..511 = w_h2h
    const float* __restrict__ b_h2h,
    const float* __restrict__ w_score,
    const int* __restrict__ text,
    unsigned short* __restrict__ hseq,
    unsigned* __restrict__ bar) {
    __shared__ __align__(16) unsigned short lB2[32 * 1032];   // 66048 B gates B-slice
    __shared__ __align__(16) char scr[18432];                 // A: e|al|hl|hp_l ; B: gbuf

    const int bid  = blockIdx.x;
    const int tid  = threadIdx.x;
    const int lane = tid & 63, wid = tid >> 6;
    const int nb = bid & 63;          // gates n-chunk (32 gate-cols)
    const int mb = bid >> 6;          // gates m-chunk (128 rows)

    // ---- one-time persistent gates-weight preload ----
    for (int u = tid; u < 4096; u += 512) {       // 32 rows x 128 chunks of 8 elems
        int r = u >> 7, cb = u & 127;
        *(i32x4*)(lB2 + r * 1032 + cb * 8) =
            *(const i32x4*)(B2r + (size_t)(nb * 32 + r) * 1024 + cb * 8);
    }

    float c0 = 0.f, c1 = 0.f;   // persistent cell state (2 units/thread)
    unsigned gen = 0;

    const unsigned short* lb0 = lB2 + (lane & 15) * 1032 + (lane >> 4) * 8;
    const unsigned short* lb1 = lb0 + 16 * 1032;
    const int gm0 = mb * 128;
    const size_t arow_off = (size_t)(gm0 + wid * 16 + (lane & 15)) * 1024 + (lane >> 4) * 8;

    float* e_lds  = (float*)scr;            // [2][64]
    float* al_lds = e_lds + 128;            // [2][64]
    float* hl     = (float*)(scr + 1024);   // [512][2]  h interleaved by k
    float* hp_l   = (float*)(scr + 5120);   // [2][512]  hp result
    float* gbuf   = (float*)scr;            // [128][36] (phase B, after barrier)

    for (int s = 0; s < STEPS; ++s) {
        unsigned short* A2cur = A2 + (size_t)(s & 1) * BATCH * 1024;
        unsigned short* A2nxt = A2 + (size_t)((s + 1) & 1) * BATCH * 1024;

        // ---- phase A.1: issue gates h-half loads (h(s-1) visible since last barrier) ----
        const unsigned long long* Abh = (const unsigned long long*)(A2cur + arow_off);
        unsigned long long a0v[16], a1v[16];
        #pragma unroll
        for (int kc = 0; kc < 16; ++kc) {
            a0v[kc] = aload64(Abh + (16 + kc) * 8);
            a1v[kc] = aload64(Abh + (16 + kc) * 8 + 1);
        }

        // ---- phase A.2: this block's 2 h rows -> LDS interleaved [k][2] ----
        {
            const int r = tid >> 8, j = tid & 255;
            unsigned hv = aload((const unsigned*)(A2cur + (size_t)(bid * 2 + r) * 1024 + 512) + j);
            hl[(2 * j) * 2 + r]     = bf2f((unsigned short)(hv & 0xffffu));
            hl[(2 * j + 1) * 2 + r] = bf2f((unsigned short)(hv >> 16));
        }
        __syncthreads();

        // ---- phase A.3: hp GEMV (thread = output col n, both rows) ----
        {
            const int n = tid;
            float g0 = b_h2h[n], g1 = g0;
            const unsigned short* wr = B3 + (size_t)n * 512;   // w_h2h row n (RO, L2-hot)
            const float4* hq = (const float4*)hl;
            #pragma unroll 4
            for (int k8 = 0; k8 < 64; ++k8) {
                bf16x8 wv = *(const bf16x8*)(wr + k8 * 8);
                #pragma unroll
                for (int q = 0; q < 4; ++q) {
                    float4 hh = hq[k8 * 4 + q];   // {h0[k],h1[k],h0[k+1],h1[k+1]}
                    float w0 = bf2f((unsigned short)wv[2 * q]);
                    float w1 = bf2f((unsigned short)wv[2 * q + 1]);
                    g0 += w0 * hh.x + w1 * hh.z;
                    g1 += w0 * hh.y + w1 * hh.w;
                }
            }
            hp_l[n]       = g0;
            hp_l[512 + n] = g1;
        }

        // ---- phase A.4: gates h-half MFMA (loads long since returned) ----
        f32x4 acc0 = {}, acc1 = {};
        #pragma unroll
        for (int kc = 0; kc < 16; ++kc) {
            bf16x8 af = mk_frag(a0v[kc], a1v[kc]);
            bf16x8 b0 = *(const bf16x8*)(lb0 + (16 + kc) * 32);
            bf16x8 b1 = *(const bf16x8*)(lb1 + (16 + kc) * 32);
            acc0 = __builtin_amdgcn_mfma_f32_16x16x32_bf16(af, b0, acc0, 0, 0, 0);
            acc1 = __builtin_amdgcn_mfma_f32_16x16x32_bf16(af, b1, acc1, 0, 0, 0);
        }
        __syncthreads();   // hp_l ready for attention

        // ---- phase A.5: attention (2 batch rows/block), hp from LDS ----
        {
            const int half = tid >> 8, t4 = tid & 255, w4 = t4 >> 6;
            const int b = bid * 2 + half;
            float hp8[8], ws8[8];
            #pragma unroll
            for (int j = 0; j < 8; j++) hp8[j] = hp_l[half * 512 + lane * 8 + j];
            {
                const float4* wsp = (const float4*)(w_score + lane * 8);
                float4 w0 = wsp[0], w1 = wsp[1];
                ws8[0] = w0.x; ws8[1] = w0.y; ws8[2] = w0.z; ws8[3] = w0.w;
                ws8[4] = w1.x; ws8[5] = w1.y; ws8[6] = w1.z; ws8[7] = w1.w;
            }
            for (int t = w4; t < 64; t += 4) {
                bf16x8 hv = *(const bf16x8*)(Hp + ((size_t)b * 64 + t) * 512 + lane * 8);
                float a = 0.f;
                #pragma unroll
                for (int j = 0; j < 8; j++)
                    a += ws8[j] * tanh_f(hp8[j] + bf2f((unsigned short)hv[j]));
                #pragma unroll
                for (int off = 32; off > 0; off >>= 1) a += __shfl_down(a, off);
                if (lane == 0) e_lds[half * 64 + t] = a;
            }
            __syncthreads();
            if (w4 == 0) {   // one wave per batch row: softmax over 64 t
                float v = e_lds[half * 64 + lane];
                float m = v;
                #pragma unroll
                for (int off = 32; off > 0; off >>= 1) m = fmaxf(m, __shfl_xor(m, off));
                float ex = __expf(v - m);
                float sum = ex;
                #pragma unroll
                for (int off = 32; off > 0; off >>= 1) sum += __shfl_xor(sum, off);
                al_lds[half * 64 + lane] = ex / sum;
            }
            __syncthreads();
            float a0 = 0.f, a1 = 0.f;
            const unsigned short* erow = enc + (size_t)b * 64 * 512 + t4 * 2;
            #pragma unroll 8
            for (int t = 0; t < 64; t++) {
                float al = al_lds[half * 64 + t];
                unsigned pv = *(const unsigned*)(erow + (size_t)t * 512);
                a0 += al * bf2f((unsigned short)(pv & 0xffffu));
                a1 += al * bf2f((unsigned short)(pv >> 16));
            }
            unsigned pk = ((unsigned)f2bf(a1) << 16) | (unsigned)f2bf(a0);
            astore((unsigned*)(A2cur + (size_t)b * 1024) + t4, pk);    // coherent ctx
        }
        gbar(bar, bid, ++gen);

        // ---- phase B: gates ctx-half (K=0..511) + fused LSTM ----
        {
            const unsigned long long* Ab = (const unsigned long long*)(A2cur + arow_off);
            unsigned long long b0v[16], b1v[16];
            #pragma unroll
            for (int kc = 0; kc < 16; ++kc) {
                b0v[kc] = aload64(Ab + kc * 8);
                b1v[kc] = aload64(Ab + kc * 8 + 1);
            }
            #pragma unroll
            for (int kc = 0; kc < 16; ++kc) {
                bf16x8 af = mk_frag(b0v[kc], b1v[kc]);
                bf16x8 b0 = *(const bf16x8*)(lb0 + kc * 32);
                bf16x8 b1 = *(const bf16x8*)(lb1 + kc * 32);
                acc0 = __builtin_amdgcn_mfma_f32_16x16x32_bf16(af, b0, acc0, 0, 0, 0);
                acc1 = __builtin_amdgcn_mfma_f32_16x16x32_bf16(af, b1, acc1, 0, 0, 0);
            }
            const int grow = wid * 16 + (lane >> 4) * 4;
            const int gcol = lane & 15;
            #pragma unroll
            for (int r = 0; r < 4; r++) {
                gbuf[(grow + r) * 36 + gcol]      = acc0[r];
                gbuf[(grow + r) * 36 + 16 + gcol] = acc1[r];
            }
            __syncthreads();
            {   // LSTM pointwise: thread -> (row, unit pair); c in registers
                const int rl = tid >> 2, q = tid & 3;
                const int b = gm0 + rl;
                const int npb = nb * 32 + q * 8;       // gate-slot base (2 units)
                const int u0 = npb >> 2;
                const int tb = text[b * STEPS + s];
                const float* gr = gbuf + rl * 36 + q * 8;
                float4 g0 = *(const float4*)gr;
                float4 g1 = *(const float4*)(gr + 4);
                float vi0 = g0.x + bias2r[npb + 0] + woh[(npb + 0) * NCLS + tb];
                float vf0 = g0.y + bias2r[npb + 1] + woh[(npb + 1) * NCLS + tb];
                float vg0 = g0.z + bias2r[npb + 2] + woh[(npb + 2) * NCLS + tb];
                float vo0 = g0.w + bias2r[npb + 3] + woh[(npb + 3) * NCLS + tb];
                float vi1 = g1.x + bias2r[npb + 4] + woh[(npb + 4) * NCLS + tb];
                float vf1 = g1.y + bias2r[npb + 5] + woh[(npb + 5) * NCLS + tb];
                float vg1 = g1.z + bias2r[npb + 6] + woh[(npb + 6) * NCLS + tb];
                float vo1 = g1.w + bias2r[npb + 7] + woh[(npb + 7) * NCLS + tb];
                float cn0 = sigmoid_f(vf0) * c0 + sigmoid_f(vi0) * tanh_f(vg0);
                float cn1 = sigmoid_f(vf1) * c1 + sigmoid_f(vi1) * tanh_f(vg1);
                c0 = cn0; c1 = cn1;
                float hn0 = sigmoid_f(vo0) * tanh_f(cn0);
                float hn1 = sigmoid_f(vo1) * tanh_f(cn1);
                unsigned hp2 = ((unsigned)f2bf(hn1) << 16) | (unsigned)f2bf(hn0);
                astore((unsigned*)(A2nxt + (size_t)b * 1024 + 512 + u0), hp2);  // coherent h
                *(unsigned*)(hseq + ((size_t)s * BATCH + b) * 512 + u0) = hp2;  // post-kernel only
            }
        }
        if (s + 1 < STEPS) gbar(bar, bid, ++gen);
    }
}

// ---------------- host ----------------
extern "C" void kernel_launch(void* const* d_in, const int* in_sizes, int n_in,
                              void* d_out, int out_size, void* d_ws, size_t ws_size,
                              hipStream_t stream) {
    (void)in_sizes; (void)n_in; (void)out_size; (void)ws_size;
    const float* enc_f   = (const float*)d_in[0];
    const int*   text    = (const int*)d_in[1];
    const float* w_i2h   = (const float*)d_in[2];
    const float* w_h2h   = (const float*)d_in[3];
    const float* b_h2h   = (const float*)d_in[4];
    const float* w_score = (const float*)d_in[5];
    const float* w_ih    = (const float*)d_in[6];
    const float* w_hh    = (const float*)d_in[7];
    const float* b_ih    = (const float*)d_in[8];
    const float* b_hh    = (const float*)d_in[9];
    const float* w_gen   = (const float*)d_in[10];
    const float* b_gen   = (const float*)d_in[11];
    float* out = (float*)d_out;

    char* ws = (char*)d_ws;
    const unsigned short* Hp     = (const unsigned short*)(ws + HP_OFF);
    unsigned short*       Hp_w   = (unsigned short*)(ws + HP_OFF);
    const unsigned short* encb   = (const unsigned short*)(ws + ENC_OFF);
    unsigned short*       encb_w = (unsigned short*)(ws + ENC_OFF);
    unsigned short*       A2     = (unsigned short*)(ws + A2_OFF);
    const unsigned short* B2r    = (const unsigned short*)(ws + B2R_OFF);
    unsigned short*       B2r_w  = (unsigned short*)(ws + B2R_OFF);
    unsigned short*       wi2hb  = (unsigned short*)(ws + WI2H_OFF);
    const unsigned short* B3     = (const unsigned short*)(ws + B3_OFF);
    unsigned short*       B3_w   = (unsigned short*)(ws + B3_OFF);
    const float*          woh    = (const float*)(ws + WOH_OFF);
    float*                woh_w  = (float*)(ws + WOH_OFF);
    const float*          bias2r = (const float*)(ws + BIAS_OFF);
    float*                bias2r_w = (float*)(ws + BIAS_OFF);
    unsigned short*       hseq   = (unsigned short*)(ws + HSEQ_OFF);
    unsigned*             bar    = (unsigned*)(ws + BAR_OFF);

    conv_bf16_kernel<<<2048, 256, 0, stream>>>(enc_f, encb_w, BATCH * TENC * DIN / 4);
    conv_bf16_kernel<<<256, 256, 0, stream>>>(w_i2h, wi2hb, HDIM * DIN / 4);
    build_b2r_kernel<<<NG, 256, 0, stream>>>(w_ih, w_hh, b_ih, b_hh, B2r_w, woh_w, bias2r_w);
    build_b3_kernel<<<576, 256, 0, stream>>>(w_h2h, w_gen, B3_w);
    init_state_kernel<<<BATCH, 256, 0, stream>>>(A2, bar);

    // H_proj = enc @ w_i2h^T  (M=32768, N=512, K=512)
    gemm_bf16out_kernel<<<dim3(BATCH * TENC / 128, HDIM / 128), 256, 0, stream>>>(
        encb, DIN, wi2hb, DIN, Hp_w, HDIM, DIN);

    // cooperative decode: all 26 steps, 2 barriers/step
    {
        void* args[12] = {
            (void*)&Hp, (void*)&encb, (void*)&A2,
            (void*)&B2r, (void*)&bias2r, (void*)&woh, (void*)&B3,
            (void*)&b_h2h, (void*)&w_score, (void*)&text, (void*)&hseq, (void*)&bar
        };
        hipLaunchCooperativeKernel((const void*)decode_kernel, dim3(256), dim3(512),
                                   args, 0, stream);
    }

    // probs = hseq @ [w_gen;0]^T + b_gen  (M = S*B = 13312, N = 64, K = 512)
    probs_kernel<<<dim3(STEPS * BATCH / 64), 256, 0, stream>>>(
        hseq, B3 + (size_t)512 * 512, b_gen, out);
}

// Round 12
// 1946.371 us; speedup vs baseline: 1.0022x; 1.0022x over previous
//
#include <hip/hip_runtime.h>

typedef __attribute__((ext_vector_type(8))) short bf16x8;
typedef __attribute__((ext_vector_type(4))) float f32x4;
typedef __attribute__((ext_vector_type(4))) int   i32x4;

#define DEV static __device__ __forceinline__

constexpr int BATCH = 512;
constexpr int TENC  = 64;
constexpr int DIN   = 512;
constexpr int HDIM  = 512;
constexpr int NCLS  = 38;
constexpr int STEPS = 26;
constexpr int NG    = 4 * HDIM;   // 2048

// ---- workspace layout (bytes) ----
constexpr size_t HP_OFF   = 0;                                   // bf16 [B*T][512]  H_proj
constexpr size_t HP_SZ    = (size_t)BATCH * TENC * HDIM * 2;
constexpr size_t ENC_OFF  = HP_OFF + HP_SZ;                      // bf16 [B*T][512]  encoder
constexpr size_t ENC_SZ   = (size_t)BATCH * TENC * DIN * 2;
constexpr size_t A2_OFF   = ENC_OFF + ENC_SZ;                    // bf16 [2][B][1024] ping-pong [ctx | h]
constexpr size_t A2_SZ    = (size_t)2 * BATCH * 1024 * 2;
constexpr size_t B2R_OFF  = A2_OFF + A2_SZ;                      // bf16 [2048][1024] gate-interleaved (RO)
constexpr size_t B2R_SZ   = (size_t)NG * 1024 * 2;
constexpr size_t WI2H_OFF = B2R_OFF + B2R_SZ;                    // bf16 [512][512] (RO)
constexpr size_t WI2H_SZ  = (size_t)HDIM * DIN * 2;
constexpr size_t B3_OFF   = WI2H_OFF + WI2H_SZ;                  // bf16 [576][512]  [w_h2h ; w_gen ; pad] (RO)
constexpr size_t B3_SZ    = (size_t)576 * HDIM * 2;
constexpr size_t WOH_OFF  = B3_OFF + B3_SZ;                      // f32 [2048][38] (RO)
constexpr size_t WOH_SZ   = (size_t)NG * NCLS * 4;
constexpr size_t BIAS_OFF = WOH_OFF + WOH_SZ;                    // f32 [2048] (RO)
constexpr size_t BIAS_SZ  = (size_t)NG * 4;
constexpr size_t HSEQ_OFF = BIAS_OFF + BIAS_SZ;                  // bf16 [S][B][512] (read post-decode only)
constexpr size_t HSEQ_SZ  = (size_t)STEPS * BATCH * HDIM * 2;
constexpr size_t BAR_OFF  = HSEQ_OFF + HSEQ_SZ;                  // u32 barrier state
constexpr size_t BAR_SZ   = 16384;

DEV float bf2f(unsigned short s) {
    unsigned u = ((unsigned)s) << 16;
    return __builtin_bit_cast(float, u);
}
DEV unsigned short f2bf(float f) {
    unsigned u = __builtin_bit_cast(unsigned, f);
    u = (u + 0x7fffu + ((u >> 16) & 1u)) >> 16;   // RNE
    return (unsigned short)u;
}
DEV float sigmoid_f(float x) { return 1.f / (1.f + __expf(-x)); }
DEV float tanh_f(float x) {
    x = fminf(fmaxf(x, -15.f), 15.f);
    float e = __expf(2.f * x);
    return (e - 1.f) / (e + 1.f);
}

DEV unsigned aload(const unsigned* p) {
    return __hip_atomic_load(p, __ATOMIC_RELAXED, __HIP_MEMORY_SCOPE_AGENT);
}
DEV unsigned long long aload64(const unsigned long long* p) {
    return __hip_atomic_load(p, __ATOMIC_RELAXED, __HIP_MEMORY_SCOPE_AGENT);
}
DEV void astore(unsigned* p, unsigned v) {
    __hip_atomic_store(p, v, __ATOMIC_RELAXED, __HIP_MEMORY_SCOPE_AGENT);
}
DEV bf16x8 mk_frag(unsigned long long lo, unsigned long long hi) {
    union { unsigned long long q[2]; bf16x8 v; } u;
    u.q[0] = lo; u.q[1] = hi;
    return u.v;
}

// ---------- monotonic grid barrier with throttled poll (256 blocks: 32 x 8) ----------
// Counters only increment (gen g: sub target g*8-1, root target g*32-1) -> no
// reset stores / no vmcnt on the critical path. Pollers throttle with s_sleep(1)
// (round-8 vs round-10 A/B: un-throttled polling saturates the MALL and slows
// the flip propagation; sleep-throttled was 1303us vs 1534us busy-poll).
DEV void gbar(unsigned* bar, int bid, unsigned g) {
    __syncthreads();                 // drains this block's stores (vmcnt 0)
    if (threadIdx.x == 0) {
        const int sg = bid & 31;
        unsigned* sub  = bar + sg * 32;
        unsigned* root = bar + 1024;
        unsigned* genp = bar + 1056 + sg * 32;
        bool flipped = false;
        if (__hip_atomic_fetch_add(sub, 1u, __ATOMIC_RELAXED, __HIP_MEMORY_SCOPE_AGENT) == g * 8u - 1u) {
            if (__hip_atomic_fetch_add(root, 1u, __ATOMIC_RELAXED, __HIP_MEMORY_SCOPE_AGENT) == g * 32u - 1u) {
                #pragma unroll
                for (int i = 0; i < 32; i++) astore(bar + 1056 + i * 32, g);
                flipped = true;
            }
        }
        if (!flipped) {
            while (aload(genp) < g) __builtin_amdgcn_s_sleep(1);
        }
    }
    __syncthreads();
}

// ---------------- conversion / init kernels ----------------
__global__ void conv_bf16_kernel(const float* __restrict__ in,
                                 unsigned short* __restrict__ out, int n4) {
    int i = blockIdx.x * blockDim.x + threadIdx.x;
    int stride = gridDim.x * blockDim.x;
    for (; i < n4; i += stride) {
        float4 v = ((const float4*)in)[i];
        ushort4 o;
        o.x = f2bf(v.x); o.y = f2bf(v.y); o.z = f2bf(v.z); o.w = f2bf(v.w);
        ((ushort4*)out)[i] = o;
    }
}

__global__ void build_b2r_kernel(const float* __restrict__ w_ih, const float* __restrict__ w_hh,
                                 const float* __restrict__ b_ih, const float* __restrict__ b_hh,
                                 unsigned short* __restrict__ B2r, float* __restrict__ woh,
                                 float* __restrict__ bias2r) {
    int np = blockIdx.x;            // 0..2047 (n' = u*4+g)
    int u = np >> 2, g = np & 3;
    int src = g * 512 + u;
    for (int k = threadIdx.x; k < 512; k += blockDim.x) {
        B2r[np * 1024 + k]       = f2bf(w_ih[src * 550 + k]);
        B2r[np * 1024 + 512 + k] = f2bf(w_hh[src * 512 + k]);
    }
    if (threadIdx.x < NCLS) woh[np * NCLS + threadIdx.x] = w_ih[src * 550 + 512 + threadIdx.x];
    if (threadIdx.x == 0)   bias2r[np] = b_ih[src] + b_hh[src];
}

__global__ void build_b3_kernel(const float* __restrict__ w_h2h, const float* __restrict__ w_gen,
                                unsigned short* __restrict__ B3) {
    int n = blockIdx.x;             // 0..575
    for (int k = threadIdx.x; k < 512; k += blockDim.x) {
        float v = 0.f;
        if (n < 512)      v = w_h2h[n * 512 + k];
        else if (n < 550) v = w_gen[(n - 512) * 512 + k];
        B3[n * 512 + k] = f2bf(v);
    }
}

__global__ void init_state_kernel(unsigned short* __restrict__ A2,
                                  unsigned* __restrict__ bar) {
    int b = blockIdx.x;
    for (int j = threadIdx.x; j < 512; j += blockDim.x)
        A2[b * 1024 + 512 + j] = 0;            // h part of buffer 0 = 0
    if (b == 0)
        for (int j = threadIdx.x; j < 2112; j += blockDim.x) bar[j] = 0;
}

// ---------------- generic MFMA GEMM core (used by H_proj / probs) ----------------
template<int BM, int BN, int WN, int FRM, int FRN>
DEV void gemm_core(const unsigned short* __restrict__ A, int ldA,
                   const unsigned short* __restrict__ Bm, int ldB, int K,
                   int m0, int n0, unsigned short* __restrict__ lA,
                   unsigned short* __restrict__ lB, f32x4 acc[FRM][FRN]) {
    constexpr int LSTR = 40;
    const int tid  = threadIdx.x;
    const int lane = tid & 63;
    const int wid  = tid >> 6;
    const int wm = wid / WN, wn = wid % WN;
    const int fr_row = lane & 15;
    const int fr_kb  = (lane >> 4) * 8;

    for (int k0 = 0; k0 < K; k0 += 32) {
        for (int u = tid; u < BM * 4; u += 256) {
            int r = u >> 2, cb = u & 3;
            *(i32x4*)(lA + r * LSTR + cb * 8) =
                *(const i32x4*)(A + (size_t)(m0 + r) * ldA + k0 + cb * 8);
        }
        for (int u = tid; u < BN * 4; u += 256) {
            int r = u >> 2, cb = u & 3;
            *(i32x4*)(lB + r * LSTR + cb * 8) =
                *(const i32x4*)(Bm + (size_t)(n0 + r) * ldB + k0 + cb * 8);
        }
        __syncthreads();
        bf16x8 af[FRM], bfv[FRN];
        #pragma unroll
        for (int i = 0; i < FRM; i++)
            af[i] = *(const bf16x8*)(lA + (wm * FRM * 16 + i * 16 + fr_row) * LSTR + fr_kb);
        #pragma unroll
        for (int j = 0; j < FRN; j++)
            bfv[j] = *(const bf16x8*)(lB + (wn * FRN * 16 + j * 16 + fr_row) * LSTR + fr_kb);
        #pragma unroll
        for (int i = 0; i < FRM; i++)
            #pragma unroll
            for (int j = 0; j < FRN; j++)
                acc[i][j] = __builtin_amdgcn_mfma_f32_16x16x32_bf16(af[i], bfv[j], acc[i][j], 0, 0, 0);
        __syncthreads();
    }
}

// ---------------- H_proj GEMM (bf16 output) ----------------
__global__ __launch_bounds__(256) void gemm_bf16out_kernel(
    const unsigned short* __restrict__ A, int ldA,
    const unsigned short* __restrict__ Bm, int ldB,
    unsigned short* __restrict__ C, int ldC, int K) {
    constexpr int BM = 128, BN = 128, FRM = 4, FRN = 4;
    __shared__ __align__(16) unsigned short lA[BM * 40], lB[BN * 40];
    int m0 = blockIdx.x * BM, n0 = blockIdx.y * BN;
    f32x4 acc[FRM][FRN] = {};
    gemm_core<BM, BN, 2, FRM, FRN>(A, ldA, Bm, ldB, K, m0, n0, lA, lB, acc);
    const int lane = threadIdx.x & 63, wid = threadIdx.x >> 6;
    const int wm = wid >> 1, wn = wid & 1;
    #pragma unroll
    for (int i = 0; i < FRM; i++)
        #pragma unroll
        for (int j = 0; j < FRN; j++)
            #pragma unroll
            for (int r = 0; r < 4; r++) {
                int m = m0 + wm * FRM * 16 + i * 16 + (lane >> 4) * 4 + r;
                int n = n0 + wn * FRN * 16 + j * 16 + (lane & 15);
                C[(size_t)m * ldC + n] = f2bf(acc[i][j][r]);
            }
}

// ---------------- final probs GEMM ----------------
__global__ __launch_bounds__(256) void probs_kernel(
    const unsigned short* __restrict__ hseq,   // [S*B][512] bf16
    const unsigned short* __restrict__ Bg,     // [64][512]  bf16 (w_gen padded)
    const float* __restrict__ b_gen, float* __restrict__ out) {
    __shared__ __align__(16) unsigned short lA[64 * 40], lB[64 * 40];
    int m0 = blockIdx.x * 64;
    f32x4 acc[2][2] = {};
    gemm_core<64, 64, 2, 2, 2>(hseq, 512, Bg, 512, 512, m0, 0, lA, lB, acc);
    const int lane = threadIdx.x & 63, wid = threadIdx.x >> 6;
    const int wm = wid >> 1, wn = wid & 1;
    #pragma unroll
    for (int i = 0; i < 2; i++)
        #pragma unroll
        for (int j = 0; j < 2; j++)
            #pragma unroll
            for (int r = 0; r < 4; r++) {
                int m = m0 + wm * 32 + i * 16 + (lane >> 4) * 4 + r;
                int n = wn * 32 + j * 16 + (lane & 15);
                if (n < NCLS) {
                    int ss = m >> 9, b = m & 511;   // hseq row = s*512 + b
                    out[((size_t)b * STEPS + ss) * NCLS + n] = acc[i][j][r] + b_gen[n];
                }
            }
}

// ---------------- cooperative decode: 256 blocks x 512 threads, 2 barriers/step ----------------
// Phase A (per block, its 2 batch rows): hp = h@w_h2h^T + b (local GEMV, w_h2h
// streamed from L2, hp kept in LDS) -> attention -> ctx store. Also overlaps the
// gates h-half MFMA (depends only on h(s-1)). Phase B: gates ctx-half + LSTM.
// hp32 global buffer and the phase-3 GEMM + its barrier are GONE.
__global__ __launch_bounds__(512, 2) void decode_kernel(
    const unsigned short* __restrict__ Hp,
    const unsigned short* __restrict__ enc,
    unsigned short* __restrict__ A2,       // [2][B][1024]
    const unsigned short* __restrict__ B2r,
    const float* __restrict__ bias2r,
    const float* __restrict__ woh,
    const unsigned short* __restrict__ B3, // rows 0..511 = w_h2h
    const float* __restrict__ b_h2h,
    const float* __restrict__ w_score,
    const int* __restrict__ text,
    unsigned short* __restrict__ hseq,
    unsigned* __restrict__ bar) {
    __shared__ __align__(16) unsigned short lB2[32 * 1032];   // 66048 B gates B-slice
    __shared__ __align__(16) char scr[18432];                 // A: e|al|hl|hp_l ; B: gbuf

    const int bid  = blockIdx.x;
    const int tid  = threadIdx.x;
    const int lane = tid & 63, wid = tid >> 6;
    const int nb = bid & 63;          // gates n-chunk (32 gate-cols)
    const int mb = bid >> 6;          // gates m-chunk (128 rows)

    // ---- one-time persistent gates-weight preload ----
    for (int u = tid; u < 4096; u += 512) {       // 32 rows x 128 chunks of 8 elems
        int r = u >> 7, cb = u & 127;
        *(i32x4*)(lB2 + r * 1032 + cb * 8) =
            *(const i32x4*)(B2r + (size_t)(nb * 32 + r) * 1024 + cb * 8);
    }

    float c0 = 0.f, c1 = 0.f;   // persistent cell state (2 units/thread)
    unsigned gen = 0;

    const unsigned short* lb0 = lB2 + (lane & 15) * 1032 + (lane >> 4) * 8;
    const unsigned short* lb1 = lb0 + 16 * 1032;
    const int gm0 = mb * 128;
    const size_t arow_off = (size_t)(gm0 + wid * 16 + (lane & 15)) * 1024 + (lane >> 4) * 8;

    float* e_lds  = (float*)scr;            // [2][64]
    float* al_lds = e_lds + 128;            // [2][64]
    float* hl     = (float*)(scr + 1024);   // [512][2]  h interleaved by k
    float* hp_l   = (float*)(scr + 5120);   // [2][512]  hp result
    float* gbuf   = (float*)scr;            // [128][36] (phase B, after barrier)

    for (int s = 0; s < STEPS; ++s) {
        unsigned short* A2cur = A2 + (size_t)(s & 1) * BATCH * 1024;
        unsigned short* A2nxt = A2 + (size_t)((s + 1) & 1) * BATCH * 1024;

        // ---- phase A.1: issue gates h-half loads (h(s-1) visible since last barrier) ----
        const unsigned long long* Abh = (const unsigned long long*)(A2cur + arow_off);
        unsigned long long a0v[16], a1v[16];
        #pragma unroll
        for (int kc = 0; kc < 16; ++kc) {
            a0v[kc] = aload64(Abh + (16 + kc) * 8);
            a1v[kc] = aload64(Abh + (16 + kc) * 8 + 1);
        }

        // ---- phase A.2: this block's 2 h rows -> LDS interleaved [k][2] ----
        {
            const int r = tid >> 8, j = tid & 255;
            unsigned hv = aload((const unsigned*)(A2cur + (size_t)(bid * 2 + r) * 1024 + 512) + j);
            hl[(2 * j) * 2 + r]     = bf2f((unsigned short)(hv & 0xffffu));
            hl[(2 * j + 1) * 2 + r] = bf2f((unsigned short)(hv >> 16));
        }
        __syncthreads();

        // ---- phase A.3: hp GEMV (thread = output col n, both rows) ----
        {
            const int n = tid;
            float g0 = b_h2h[n], g1 = g0;
            const unsigned short* wr = B3 + (size_t)n * 512;   // w_h2h row n (RO, L2-hot)
            const float4* hq = (const float4*)hl;
            #pragma unroll 4
            for (int k8 = 0; k8 < 64; ++k8) {
                bf16x8 wv = *(const bf16x8*)(wr + k8 * 8);
                #pragma unroll
                for (int q = 0; q < 4; ++q) {
                    float4 hh = hq[k8 * 4 + q];   // {h0[k],h1[k],h0[k+1],h1[k+1]}
                    float w0 = bf2f((unsigned short)wv[2 * q]);
                    float w1 = bf2f((unsigned short)wv[2 * q + 1]);
                    g0 += w0 * hh.x + w1 * hh.z;
                    g1 += w0 * hh.y + w1 * hh.w;
                }
            }
            hp_l[n]       = g0;
            hp_l[512 + n] = g1;
        }

        // ---- phase A.4: gates h-half MFMA (loads long since returned) ----
        f32x4 acc0 = {}, acc1 = {};
        #pragma unroll
        for (int kc = 0; kc < 16; ++kc) {
            bf16x8 af = mk_frag(a0v[kc], a1v[kc]);
            bf16x8 b0 = *(const bf16x8*)(lb0 + (16 + kc) * 32);
            bf16x8 b1 = *(const bf16x8*)(lb1 + (16 + kc) * 32);
            acc0 = __builtin_amdgcn_mfma_f32_16x16x32_bf16(af, b0, acc0, 0, 0, 0);
            acc1 = __builtin_amdgcn_mfma_f32_16x16x32_bf16(af, b1, acc1, 0, 0, 0);
        }
        __syncthreads();   // hp_l ready for attention

        // ---- phase A.5: attention (2 batch rows/block), hp from LDS ----
        {
            const int half = tid >> 8, t4 = tid & 255, w4 = t4 >> 6;
            const int b = bid * 2 + half;
            float hp8[8], ws8[8];
            #pragma unroll
            for (int j = 0; j < 8; j++) hp8[j] = hp_l[half * 512 + lane * 8 + j];
            {
                const float4* wsp = (const float4*)(w_score + lane * 8);
                float4 w0 = wsp[0], w1 = wsp[1];
                ws8[0] = w0.x; ws8[1] = w0.y; ws8[2] = w0.z; ws8[3] = w0.w;
                ws8[4] = w1.x; ws8[5] = w1.y; ws8[6] = w1.z; ws8[7] = w1.w;
            }
            for (int t = w4; t < 64; t += 4) {
                bf16x8 hv = *(const bf16x8*)(Hp + ((size_t)b * 64 + t) * 512 + lane * 8);
                float a = 0.f;
                #pragma unroll
                for (int j = 0; j < 8; j++)
                    a += ws8[j] * tanh_f(hp8[j] + bf2f((unsigned short)hv[j]));
                #pragma unroll
                for (int off = 32; off > 0; off >>= 1) a += __shfl_down(a, off);
                if (lane == 0) e_lds[half * 64 + t] = a;
            }
            __syncthreads();
            if (w4 == 0) {   // one wave per batch row: softmax over 64 t
                float v = e_lds[half * 64 + lane];
                float m = v;
                #pragma unroll
                for (int off = 32; off > 0; off >>= 1) m = fmaxf(m, __shfl_xor(m, off));
                float ex = __expf(v - m);
                float sum = ex;
                #pragma unroll
                for (int off = 32; off > 0; off >>= 1) sum += __shfl_xor(sum, off);
                al_lds[half * 64 + lane] = ex / sum;
            }
            __syncthreads();
            float a0 = 0.f, a1 = 0.f;
            const unsigned short* erow = enc + (size_t)b * 64 * 512 + t4 * 2;
            #pragma unroll 8
            for (int t = 0; t < 64; t++) {
                float al = al_lds[half * 64 + t];
                unsigned pv = *(const unsigned*)(erow + (size_t)t * 512);
                a0 += al * bf2f((unsigned short)(pv & 0xffffu));
                a1 += al * bf2f((unsigned short)(pv >> 16));
            }
            unsigned pk = ((unsigned)f2bf(a1) << 16) | (unsigned)f2bf(a0);
            astore((unsigned*)(A2cur + (size_t)b * 1024) + t4, pk);    // coherent ctx
        }
        gbar(bar, bid, ++gen);

        // ---- phase B: gates ctx-half (K=0..511) + fused LSTM ----
        {
            const unsigned long long* Ab = (const unsigned long long*)(A2cur + arow_off);
            unsigned long long b0v[16], b1v[16];
            #pragma unroll
            for (int kc = 0; kc < 16; ++kc) {
                b0v[kc] = aload64(Ab + kc * 8);
                b1v[kc] = aload64(Ab + kc * 8 + 1);
            }
            #pragma unroll
            for (int kc = 0; kc < 16; ++kc) {
                bf16x8 af = mk_frag(b0v[kc], b1v[kc]);
                bf16x8 b0 = *(const bf16x8*)(lb0 + kc * 32);
                bf16x8 b1 = *(const bf16x8*)(lb1 + kc * 32);
                acc0 = __builtin_amdgcn_mfma_f32_16x16x32_bf16(af, b0, acc0, 0, 0, 0);
                acc1 = __builtin_amdgcn_mfma_f32_16x16x32_bf16(af, b1, acc1, 0, 0, 0);
            }
            const int grow = wid * 16 + (lane >> 4) * 4;
            const int gcol = lane & 15;
            #pragma unroll
            for (int r = 0; r < 4; r++) {
                gbuf[(grow + r) * 36 + gcol]      = acc0[r];
                gbuf[(grow + r) * 36 + 16 + gcol] = acc1[r];
            }
            __syncthreads();
            {   // LSTM pointwise: thread -> (row, unit pair); c in registers
                const int rl = tid >> 2, q = tid & 3;
                const int b = gm0 + rl;
                const int npb = nb * 32 + q * 8;       // gate-slot base (2 units)
                const int u0 = npb >> 2;
                const int tb = text[b * STEPS + s];
                const float* gr = gbuf + rl * 36 + q * 8;
                float4 g0 = *(const float4*)gr;
                float4 g1 = *(const float4*)(gr + 4);
                float vi0 = g0.x + bias2r[npb + 0] + woh[(npb + 0) * NCLS + tb];
                float vf0 = g0.y + bias2r[npb + 1] + woh[(npb + 1) * NCLS + tb];
                float vg0 = g0.z + bias2r[npb + 2] + woh[(npb + 2) * NCLS + tb];
                float vo0 = g0.w + bias2r[npb + 3] + woh[(npb + 3) * NCLS + tb];
                float vi1 = g1.x + bias2r[npb + 4] + woh[(npb + 4) * NCLS + tb];
                float vf1 = g1.y + bias2r[npb + 5] + woh[(npb + 5) * NCLS + tb];
                float vg1 = g1.z + bias2r[npb + 6] + woh[(npb + 6) * NCLS + tb];
                float vo1 = g1.w + bias2r[npb + 7] + woh[(npb + 7) * NCLS + tb];
                float cn0 = sigmoid_f(vf0) * c0 + sigmoid_f(vi0) * tanh_f(vg0);
                float cn1 = sigmoid_f(vf1) * c1 + sigmoid_f(vi1) * tanh_f(vg1);
                c0 = cn0; c1 = cn1;
                float hn0 = sigmoid_f(vo0) * tanh_f(cn0);
                float hn1 = sigmoid_f(vo1) * tanh_f(cn1);
                unsigned hp2 = ((unsigned)f2bf(hn1) << 16) | (unsigned)f2bf(hn0);
                astore((unsigned*)(A2nxt + (size_t)b * 1024 + 512 + u0), hp2);  // coherent h
                *(unsigned*)(hseq + ((size_t)s * BATCH + b) * 512 + u0) = hp2;  // post-kernel only
            }
        }
        if (s + 1 < STEPS) gbar(bar, bid, ++gen);
    }
}

// ---------------- host ----------------
extern "C" void kernel_launch(void* const* d_in, const int* in_sizes, int n_in,
                              void* d_out, int out_size, void* d_ws, size_t ws_size,
                              hipStream_t stream) {
    (void)in_sizes; (void)n_in; (void)out_size; (void)ws_size;
    const float* enc_f   = (const float*)d_in[0];
    const int*   text    = (const int*)d_in[1];
    const float* w_i2h   = (const float*)d_in[2];
    const float* w_h2h   = (const float*)d_in[3];
    const float* b_h2h   = (const float*)d_in[4];
    const float* w_score = (const float*)d_in[5];
    const float* w_ih    = (const float*)d_in[6];
    const float* w_hh    = (const float*)d_in[7];
    const float* b_ih    = (const float*)d_in[8];
    const float* b_hh    = (const float*)d_in[9];
    const float* w_gen   = (const float*)d_in[10];
    const float* b_gen   = (const float*)d_in[11];
    float* out = (float*)d_out;

    char* ws = (char*)d_ws;
    const unsigned short* Hp     = (const unsigned short*)(ws + HP_OFF);
    unsigned short*       Hp_w   = (unsigned short*)(ws + HP_OFF);
    const unsigned short* encb   = (const unsigned short*)(ws + ENC_OFF);
    unsigned short*       encb_w = (unsigned short*)(ws + ENC_OFF);
    unsigned short*       A2     = (unsigned short*)(ws + A2_OFF);
    const unsigned short* B2r    = (const unsigned short*)(ws + B2R_OFF);
    unsigned short*       B2r_w  = (unsigned short*)(ws + B2R_OFF);
    unsigned short*       wi2hb  = (unsigned short*)(ws + WI2H_OFF);
    const unsigned short* B3     = (const unsigned short*)(ws + B3_OFF);
    unsigned short*       B3_w   = (unsigned short*)(ws + B3_OFF);
    const float*          woh    = (const float*)(ws + WOH_OFF);
    float*                woh_w  = (float*)(ws + WOH_OFF);
    const float*          bias2r = (const float*)(ws + BIAS_OFF);
    float*                bias2r_w = (float*)(ws + BIAS_OFF);
    unsigned short*       hseq   = (unsigned short*)(ws + HSEQ_OFF);
    unsigned*             bar    = (unsigned*)(ws + BAR_OFF);

    conv_bf16_kernel<<<2048, 256, 0, stream>>>(enc_f, encb_w, BATCH * TENC * DIN / 4);
    conv_bf16_kernel<<<256, 256, 0, stream>>>(w_i2h, wi2hb, HDIM * DIN / 4);
    build_b2r_kernel<<<NG, 256, 0, stream>>>(w_ih, w_hh, b_ih, b_hh, B2r_w, woh_w, bias2r_w);
    build_b3_kernel<<<576, 256, 0, stream>>>(w_h2h, w_gen, B3_w);
    init_state_kernel<<<BATCH, 256, 0, stream>>>(A2, bar);

    // H_proj = enc @ w_i2h^T  (M=32768, N=512, K=512)
    gemm_bf16out_kernel<<<dim3(BATCH * TENC / 128, HDIM / 128), 256, 0, stream>>>(
        encb, DIN, wi2hb, DIN, Hp_w, HDIM, DIN);

    // cooperative decode: all 26 steps, 2 barriers/step
    {
        void* args[12] = {
            (void*)&Hp, (void*)&encb, (void*)&A2,
            (void*)&B2r, (void*)&bias2r, (void*)&woh, (void*)&B3,
            (void*)&b_h2h, (void*)&w_score, (void*)&text, (void*)&hseq, (void*)&bar
        };
        hipLaunchCooperativeKernel((const void*)decode_kernel, dim3(256), dim3(512),
                                   args, 0, stream);
    }

    // probs = hseq @ [w_gen;0]^T + b_gen  (M = S*B = 13312, N = 64, K = 512)
    probs_kernel<<<dim3(STEPS * BATCH / 64), 256, 0, stream>>>(
        hseq, B3 + (size_t)512 * 512, b_gen, out);
}

// Round 13
// 1134.377 us; speedup vs baseline: 1.7196x; 1.7158x over previous
//
#include <hip/hip_runtime.h>

typedef __attribute__((ext_vector_type(8))) short bf16x8;
typedef __attribute__((ext_vector_type(4))) float f32x4;
typedef __attribute__((ext_vector_type(4))) int   i32x4;

#define DEV static __device__ __forceinline__

constexpr int BATCH = 512;
constexpr int TENC  = 64;
constexpr int DIN   = 512;
constexpr int HDIM  = 512;
constexpr int NCLS  = 38;
constexpr int STEPS = 26;
constexpr int NG    = 4 * HDIM;   // 2048

// ---- workspace layout (bytes) ----
constexpr size_t HP_OFF   = 0;                                   // bf16 [B*T][512]  H_proj
constexpr size_t HP_SZ    = (size_t)BATCH * TENC * HDIM * 2;
constexpr size_t ENC_OFF  = HP_OFF + HP_SZ;                      // bf16 [B*T][512]  encoder
constexpr size_t ENC_SZ   = (size_t)BATCH * TENC * DIN * 2;
constexpr size_t A2_OFF   = ENC_OFF + ENC_SZ;                    // bf16 [2][B][1024] ping-pong [ctx | h]
constexpr size_t A2_SZ    = (size_t)2 * BATCH * 1024 * 2;
constexpr size_t HP32_OFF = A2_OFF + A2_SZ;                      // f32 [B][512]  hp buffer (coherent)
constexpr size_t HP32_SZ  = (size_t)BATCH * HDIM * 4;
constexpr size_t B2R_OFF  = HP32_OFF + HP32_SZ;                  // bf16 [2048][1024] gate-interleaved (RO)
constexpr size_t B2R_SZ   = (size_t)NG * 1024 * 2;
constexpr size_t WI2H_OFF = B2R_OFF + B2R_SZ;                    // bf16 [512][512] (RO)
constexpr size_t WI2H_SZ  = (size_t)HDIM * DIN * 2;
constexpr size_t B3_OFF   = WI2H_OFF + WI2H_SZ;                  // bf16 [576][512]  [w_h2h ; w_gen ; pad] (RO)
constexpr size_t B3_SZ    = (size_t)576 * HDIM * 2;
constexpr size_t WOH_OFF  = B3_OFF + B3_SZ;                      // f32 [2048][38] (RO)
constexpr size_t WOH_SZ   = (size_t)NG * NCLS * 4;
constexpr size_t BIAS_OFF = WOH_OFF + WOH_SZ;                    // f32 [2048] (RO)
constexpr size_t BIAS_SZ  = (size_t)NG * 4;
constexpr size_t HSEQ_OFF = BIAS_OFF + BIAS_SZ;                  // bf16 [S][B][512] (read post-decode only)
constexpr size_t HSEQ_SZ  = (size_t)STEPS * BATCH * HDIM * 2;
constexpr size_t BAR_OFF  = HSEQ_OFF + HSEQ_SZ;                  // u32 barrier state: 8 groups x 1024 u32
constexpr size_t BAR_SZ   = 32768;

DEV float bf2f(unsigned short s) {
    unsigned u = ((unsigned)s) << 16;
    return __builtin_bit_cast(float, u);
}
DEV unsigned short f2bf(float f) {
    unsigned u = __builtin_bit_cast(unsigned, f);
    u = (u + 0x7fffu + ((u >> 16) & 1u)) >> 16;   // RNE
    return (unsigned short)u;
}
DEV float sigmoid_f(float x) { return 1.f / (1.f + __expf(-x)); }
DEV float tanh_f(float x) {
    x = fminf(fmaxf(x, -15.f), 15.f);
    float e = __expf(2.f * x);
    return (e - 1.f) / (e + 1.f);
}

DEV unsigned aload(const unsigned* p) {
    return __hip_atomic_load(p, __ATOMIC_RELAXED, __HIP_MEMORY_SCOPE_AGENT);
}
DEV unsigned long long aload64(const unsigned long long* p) {
    return __hip_atomic_load(p, __ATOMIC_RELAXED, __HIP_MEMORY_SCOPE_AGENT);
}
DEV float aloadf(const float* p) {
    return __hip_atomic_load(p, __ATOMIC_RELAXED, __HIP_MEMORY_SCOPE_AGENT);
}
DEV void astore(unsigned* p, unsigned v) {
    __hip_atomic_store(p, v, __ATOMIC_RELAXED, __HIP_MEMORY_SCOPE_AGENT);
}
DEV void astoref(float* p, float v) {
    __hip_atomic_store(p, v, __ATOMIC_RELAXED, __HIP_MEMORY_SCOPE_AGENT);
}
DEV bf16x8 mk_frag(unsigned long long lo, unsigned long long hi) {
    union { unsigned long long q[2]; bf16x8 v; } u;
    u.q[0] = lo; u.q[1] = hi;
    return u.v;
}

// ---------- GROUP-LOCAL monotonic barrier (32 blocks: 4 subs x 8 arrivals) ----------
// The recurrence is batch-row-local, so only the 32 blocks of one 64-row group
// need to sync. Monotonic counters (gen g: sub target g*8-1, root g*4-1), no
// resets on the critical path, s_sleep(1)-throttled polling (r8-proven; r10's
// un-throttled poll saturated the fabric).
DEV void gbar(unsigned* gb, int j, unsigned g) {
    __syncthreads();                 // drains this block's stores (vmcnt 0)
    if (threadIdx.x == 0) {
        const int sg = j & 3;
        unsigned* sub  = gb + sg * 32;
        unsigned* root = gb + 128;
        unsigned* genp = gb + 160 + sg * 32;
        bool flipped = false;
        if (__hip_atomic_fetch_add(sub, 1u, __ATOMIC_RELAXED, __HIP_MEMORY_SCOPE_AGENT) == g * 8u - 1u) {
            if (__hip_atomic_fetch_add(root, 1u, __ATOMIC_RELAXED, __HIP_MEMORY_SCOPE_AGENT) == g * 4u - 1u) {
                #pragma unroll
                for (int i = 0; i < 4; i++) astore(gb + 160 + i * 32, g);
                flipped = true;
            }
        }
        if (!flipped) {
            while (aload(genp) < g) __builtin_amdgcn_s_sleep(1);
        }
    }
    __syncthreads();
}

// ---------------- conversion / init kernels ----------------
__global__ void conv_bf16_kernel(const float* __restrict__ in,
                                 unsigned short* __restrict__ out, int n4) {
    int i = blockIdx.x * blockDim.x + threadIdx.x;
    int stride = gridDim.x * blockDim.x;
    for (; i < n4; i += stride) {
        float4 v = ((const float4*)in)[i];
        ushort4 o;
        o.x = f2bf(v.x); o.y = f2bf(v.y); o.z = f2bf(v.z); o.w = f2bf(v.w);
        ((ushort4*)out)[i] = o;
    }
}

__global__ void build_b2r_kernel(const float* __restrict__ w_ih, const float* __restrict__ w_hh,
                                 const float* __restrict__ b_ih, const float* __restrict__ b_hh,
                                 unsigned short* __restrict__ B2r, float* __restrict__ woh,
                                 float* __restrict__ bias2r) {
    int np = blockIdx.x;            // 0..2047 (n' = u*4+g)
    int u = np >> 2, g = np & 3;
    int src = g * 512 + u;
    for (int k = threadIdx.x; k < 512; k += blockDim.x) {
        B2r[np * 1024 + k]       = f2bf(w_ih[src * 550 + k]);
        B2r[np * 1024 + 512 + k] = f2bf(w_hh[src * 512 + k]);
    }
    if (threadIdx.x < NCLS) woh[np * NCLS + threadIdx.x] = w_ih[src * 550 + 512 + threadIdx.x];
    if (threadIdx.x == 0)   bias2r[np] = b_ih[src] + b_hh[src];
}

__global__ void build_b3_kernel(const float* __restrict__ w_h2h, const float* __restrict__ w_gen,
                                unsigned short* __restrict__ B3) {
    int n = blockIdx.x;             // 0..575
    for (int k = threadIdx.x; k < 512; k += blockDim.x) {
        float v = 0.f;
        if (n < 512)      v = w_h2h[n * 512 + k];
        else if (n < 550) v = w_gen[(n - 512) * 512 + k];
        B3[n * 512 + k] = f2bf(v);
    }
}

__global__ void init_state_kernel(unsigned short* __restrict__ A2,
                                  unsigned* __restrict__ bar) {
    int b = blockIdx.x;
    for (int j = threadIdx.x; j < 512; j += blockDim.x)
        A2[b * 1024 + 512 + j] = 0;            // h part of buffer 0 = 0
    if (b == 0)
        for (int j = threadIdx.x; j < 8192; j += blockDim.x) bar[j] = 0;
}

// ---------------- generic MFMA GEMM core (used by H_proj / probs) ----------------
template<int BM, int BN, int WN, int FRM, int FRN>
DEV void gemm_core(const unsigned short* __restrict__ A, int ldA,
                   const unsigned short* __restrict__ Bm, int ldB, int K,
                   int m0, int n0, unsigned short* __restrict__ lA,
                   unsigned short* __restrict__ lB, f32x4 acc[FRM][FRN]) {
    constexpr int LSTR = 40;
    const int tid  = threadIdx.x;
    const int lane = tid & 63;
    const int wid  = tid >> 6;
    const int wm = wid / WN, wn = wid % WN;
    const int fr_row = lane & 15;
    const int fr_kb  = (lane >> 4) * 8;

    for (int k0 = 0; k0 < K; k0 += 32) {
        for (int u = tid; u < BM * 4; u += 256) {
            int r = u >> 2, cb = u & 3;
            *(i32x4*)(lA + r * LSTR + cb * 8) =
                *(const i32x4*)(A + (size_t)(m0 + r) * ldA + k0 + cb * 8);
        }
        for (int u = tid; u < BN * 4; u += 256) {
            int r = u >> 2, cb = u & 3;
            *(i32x4*)(lB + r * LSTR + cb * 8) =
                *(const i32x4*)(Bm + (size_t)(n0 + r) * ldB + k0 + cb * 8);
        }
        __syncthreads();
        bf16x8 af[FRM], bfv[FRN];
        #pragma unroll
        for (int i = 0; i < FRM; i++)
            af[i] = *(const bf16x8*)(lA + (wm * FRM * 16 + i * 16 + fr_row) * LSTR + fr_kb);
        #pragma unroll
        for (int j = 0; j < FRN; j++)
            bfv[j] = *(const bf16x8*)(lB + (wn * FRN * 16 + j * 16 + fr_row) * LSTR + fr_kb);
        #pragma unroll
        for (int i = 0; i < FRM; i++)
            #pragma unroll
            for (int j = 0; j < FRN; j++)
                acc[i][j] = __builtin_amdgcn_mfma_f32_16x16x32_bf16(af[i], bfv[j], acc[i][j], 0, 0, 0);
        __syncthreads();
    }
}

// ---------------- H_proj GEMM (bf16 output) ----------------
__global__ __launch_bounds__(256) void gemm_bf16out_kernel(
    const unsigned short* __restrict__ A, int ldA,
    const unsigned short* __restrict__ Bm, int ldB,
    unsigned short* __restrict__ C, int ldC, int K) {
    constexpr int BM = 128, BN = 128, FRM = 4, FRN = 4;
    __shared__ __align__(16) unsigned short lA[BM * 40], lB[BN * 40];
    int m0 = blockIdx.x * BM, n0 = blockIdx.y * BN;
    f32x4 acc[FRM][FRN] = {};
    gemm_core<BM, BN, 2, FRM, FRN>(A, ldA, Bm, ldB, K, m0, n0, lA, lB, acc);
    const int lane = threadIdx.x & 63, wid = threadIdx.x >> 6;
    const int wm = wid >> 1, wn = wid & 1;
    #pragma unroll
    for (int i = 0; i < FRM; i++)
        #pragma unroll
        for (int j = 0; j < FRN; j++)
            #pragma unroll
            for (int r = 0; r < 4; r++) {
                int m = m0 + wm * FRM * 16 + i * 16 + (lane >> 4) * 4 + r;
                int n = n0 + wn * FRN * 16 + j * 16 + (lane & 15);
                C[(size_t)m * ldC + n] = f2bf(acc[i][j][r]);
            }
}

// ---------------- final probs GEMM ----------------
__global__ __launch_bounds__(256) void probs_kernel(
    const unsigned short* __restrict__ hseq,   // [S*B][512] bf16
    const unsigned short* __restrict__ Bg,     // [64][512]  bf16 (w_gen padded)
    const float* __restrict__ b_gen, float* __restrict__ out) {
    __shared__ __align__(16) unsigned short lA[64 * 40], lB[64 * 40];
    int m0 = blockIdx.x * 64;
    f32x4 acc[2][2] = {};
    gemm_core<64, 64, 2, 2, 2>(hseq, 512, Bg, 512, 512, m0, 0, lA, lB, acc);
    const int lane = threadIdx.x & 63, wid = threadIdx.x >> 6;
    const int wm = wid >> 1, wn = wid & 1;
    #pragma unroll
    for (int i = 0; i < 2; i++)
        #pragma unroll
        for (int j = 0; j < 2; j++)
            #pragma unroll
            for (int r = 0; r < 4; r++) {
                int m = m0 + wm * 32 + i * 16 + (lane >> 4) * 4 + r;
                int n = wn * 32 + j * 16 + (lane & 15);
                if (n < NCLS) {
                    int ss = m >> 9, b = m & 511;   // hseq row = s*512 + b
                    out[((size_t)b * STEPS + ss) * NCLS + n] = acc[i][j][r] + b_gen[n];
                }
            }
}

// ---------------- cooperative decode: 8 independent groups of 32 blocks ----------------
// Group g owns batch rows [g*64, g*64+64). Block j in group: gate-cols j*64..+64
// (weights persistent in LDS, 128KB), hp-cols j*16..+16, attention rows g*64+2j..+1.
// Per step: [hp MFMA] bar [attn+ctx, gates h-half overlapped] bar [gates ctx-half
// + LSTM] bar. All barriers group-local (32 blocks). Waves: mi=wid&3 (m-tile),
// kh=wid>>2 (K-half) -> no duplicate A-fragment loads.
__global__ __launch_bounds__(512, 2) void decode_kernel(
    const unsigned short* __restrict__ Hp,
    const unsigned short* __restrict__ enc,
    unsigned short* __restrict__ A2,       // [2][B][1024]
    float* __restrict__ hpb,               // [B][512] f32 coherent
    const unsigned short* __restrict__ B2r,
    const float* __restrict__ bias2r,
    const float* __restrict__ woh,
    const unsigned short* __restrict__ B3, // rows 0..511 = w_h2h
    const float* __restrict__ b_h2h,
    const float* __restrict__ w_score,
    const int* __restrict__ text,
    unsigned short* __restrict__ hseq,
    unsigned* __restrict__ bar) {
    __shared__ __align__(16) unsigned short lB2w[64 * 1032];   // 132096 B
    __shared__ __align__(16) char scr[17408];                  // pbuf | e/al | gbuf (phase-disjoint)

    const int bid  = blockIdx.x;
    const int tid  = threadIdx.x;
    const int lane = tid & 63, wid = tid >> 6;
    const int grp = bid >> 5;         // 8 groups
    const int j   = bid & 31;         // block within group
    const int gm0 = grp * 64;         // group batch rows
    const int ng0 = j * 64;           // gate-col slice
    const int ncol0 = j * 16;         // hp-col slice
    const int mi = wid & 3;           // m-tile (16 rows)
    const int kh = wid >> 2;          // K-half
    unsigned* gb = bar + grp * 1024;

    // ---- one-time persistent gates-weight preload: [64 gate-cols][1024] ----
    for (int u = tid; u < 8192; u += 512) {
        int r = u >> 7, cb = u & 127;
        *(i32x4*)(lB2w + r * 1032 + cb * 8) =
            *(const i32x4*)(B2r + (size_t)(ng0 + r) * 1024 + cb * 8);
    }

    float c0 = 0.f, c1 = 0.f;   // persistent cell state (2 units/thread)
    unsigned gen = 0;

    float* pbuf  = (float*)scr;          // [4][16][17] (hp reduce, phase 0)
    float* e_lds = (float*)scr;          // [2][64]     (attn, phase 1)
    float* al_lds = e_lds + 128;         // [2][64]
    float* gbuf  = (float*)scr;          // [64][68]    (gates, phase 2)

    for (int s = 0; s < STEPS; ++s) {
        unsigned short* A2cur = A2 + (size_t)(s & 1) * BATCH * 1024;
        unsigned short* A2nxt = A2 + (size_t)((s + 1) & 1) * BATCH * 1024;

        // ======== phase 0: hp tile [64 rows][16 cols] = h(s-1) @ w_h2h^T + b ========
        {
            const int arow = gm0 + mi * 16 + (lane & 15);
            const unsigned long long* Ah = (const unsigned long long*)
                (A2cur + (size_t)arow * 1024 + 512 + kh * 256 + (lane >> 4) * 8);
            const unsigned short* wrow = B3 + (size_t)(ncol0 + (lane & 15)) * 512
                                            + kh * 256 + (lane >> 4) * 8;
            unsigned long long h0v[8], h1v[8];
            #pragma unroll
            for (int kc = 0; kc < 8; ++kc) {
                h0v[kc] = aload64(Ah + kc * 8);
                h1v[kc] = aload64(Ah + kc * 8 + 1);
            }
            f32x4 acc = {};
            #pragma unroll
            for (int kc = 0; kc < 8; ++kc) {
                bf16x8 af = mk_frag(h0v[kc], h1v[kc]);
                bf16x8 bf = *(const bf16x8*)(wrow + kc * 32);
                acc = __builtin_amdgcn_mfma_f32_16x16x32_bf16(af, bf, acc, 0, 0, 0);
            }
            if (kh == 1) {
                #pragma unroll
                for (int r = 0; r < 4; r++)
                    pbuf[mi * 272 + ((lane >> 4) * 4 + r) * 17 + (lane & 15)] = acc[r];
            }
            __syncthreads();
            if (kh == 0) {
                #pragma unroll
                for (int r = 0; r < 4; r++) {
                    int row = (lane >> 4) * 4 + r, col = lane & 15;
                    float v = acc[r] + pbuf[mi * 272 + row * 17 + col] + b_h2h[ncol0 + col];
                    astoref(hpb + (size_t)(gm0 + mi * 16 + row) * 512 + ncol0 + col, v);
                }
            }
        }
        gbar(gb, j, ++gen);

        // ======== phase 1: gates h-half (kh==1 waves) overlapped with attention ========
        f32x4 gacc[4] = {};
        {
            // issue gates h-half loads early (h(s-1) stable all step)
            unsigned long long g0v[16], g1v[16];
            if (kh == 1) {
                const unsigned long long* Ag = (const unsigned long long*)
                    (A2cur + (size_t)(gm0 + mi * 16 + (lane & 15)) * 1024 + 512 + (lane >> 4) * 8);
                #pragma unroll
                for (int kc = 0; kc < 16; ++kc) {
                    g0v[kc] = aload64(Ag + kc * 8);
                    g1v[kc] = aload64(Ag + kc * 8 + 1);
                }
            }

            // attention: 2 batch rows/block
            const int half = tid >> 8, t4 = tid & 255, w4 = t4 >> 6;
            const int b = gm0 + 2 * j + half;
            float hp8[8], ws8[8];
            #pragma unroll
            for (int q = 0; q < 8; q++) hp8[q] = aloadf(hpb + (size_t)b * 512 + lane * 8 + q);
            {
                const float4* wsp = (const float4*)(w_score + lane * 8);
                float4 w0 = wsp[0], w1 = wsp[1];
                ws8[0] = w0.x; ws8[1] = w0.y; ws8[2] = w0.z; ws8[3] = w0.w;
                ws8[4] = w1.x; ws8[5] = w1.y; ws8[6] = w1.z; ws8[7] = w1.w;
            }
            for (int t = w4; t < 64; t += 4) {
                bf16x8 hv = *(const bf16x8*)(Hp + ((size_t)b * 64 + t) * 512 + lane * 8);
                float a = 0.f;
                #pragma unroll
                for (int q = 0; q < 8; q++)
                    a += ws8[q] * tanh_f(hp8[q] + bf2f((unsigned short)hv[q]));
                #pragma unroll
                for (int off = 32; off > 0; off >>= 1) a += __shfl_down(a, off);
                if (lane == 0) e_lds[half * 64 + t] = a;
            }
            __syncthreads();
            if (w4 == 0) {
                float v = e_lds[half * 64 + lane];
                float m = v;
                #pragma unroll
                for (int off = 32; off > 0; off >>= 1) m = fmaxf(m, __shfl_xor(m, off));
                float ex = __expf(v - m);
                float sum = ex;
                #pragma unroll
                for (int off = 32; off > 0; off >>= 1) sum += __shfl_xor(sum, off);
                al_lds[half * 64 + lane] = ex / sum;
            }
            __syncthreads();
            float a0 = 0.f, a1 = 0.f;
            const unsigned short* erow = enc + (size_t)b * 64 * 512 + t4 * 2;
            #pragma unroll 8
            for (int t = 0; t < 64; t++) {
                float al = al_lds[half * 64 + t];
                unsigned pv = *(const unsigned*)(erow + (size_t)t * 512);
                a0 += al * bf2f((unsigned short)(pv & 0xffffu));
                a1 += al * bf2f((unsigned short)(pv >> 16));
            }
            unsigned pk = ((unsigned)f2bf(a1) << 16) | (unsigned)f2bf(a0);
            astore((unsigned*)(A2cur + (size_t)b * 1024) + t4, pk);    // coherent ctx

            // gates h-half MFMA (loads long returned; B from LDS)
            if (kh == 1) {
                #pragma unroll
                for (int kc = 0; kc < 16; ++kc) {
                    bf16x8 af = mk_frag(g0v[kc], g1v[kc]);
                    #pragma unroll
                    for (int nj = 0; nj < 4; ++nj) {
                        bf16x8 bf = *(const bf16x8*)(lB2w + (nj * 16 + (lane & 15)) * 1032
                                                     + 512 + (lane >> 4) * 8 + kc * 32);
                        gacc[nj] = __builtin_amdgcn_mfma_f32_16x16x32_bf16(af, bf, gacc[nj], 0, 0, 0);
                    }
                }
            }
        }
        gbar(gb, j, ++gen);

        // ======== phase 2: gates ctx-half (kh==0 waves) + reduce + LSTM ========
        {
            if (kh == 0) {
                const unsigned long long* Ac = (const unsigned long long*)
                    (A2cur + (size_t)(gm0 + mi * 16 + (lane & 15)) * 1024 + (lane >> 4) * 8);
                unsigned long long c0v[16], c1v[16];
                #pragma unroll
                for (int kc = 0; kc < 16; ++kc) {
                    c0v[kc] = aload64(Ac + kc * 8);
                    c1v[kc] = aload64(Ac + kc * 8 + 1);
                }
                #pragma unroll
                for (int kc = 0; kc < 16; ++kc) {
                    bf16x8 af = mk_frag(c0v[kc], c1v[kc]);
                    #pragma unroll
                    for (int nj = 0; nj < 4; ++nj) {
                        bf16x8 bf = *(const bf16x8*)(lB2w + (nj * 16 + (lane & 15)) * 1032
                                                     + (lane >> 4) * 8 + kc * 32);
                        gacc[nj] = __builtin_amdgcn_mfma_f32_16x16x32_bf16(af, bf, gacc[nj], 0, 0, 0);
                    }
                }
            }
            // reduce: kh=1 writes its half, kh=0 adds
            const int grow = mi * 16 + (lane >> 4) * 4;
            const int gcol = lane & 15;
            if (kh == 1) {
                #pragma unroll
                for (int nj = 0; nj < 4; ++nj)
                    #pragma unroll
                    for (int r = 0; r < 4; r++)
                        gbuf[(grow + r) * 68 + nj * 16 + gcol] = gacc[nj][r];
            }
            __syncthreads();
            if (kh == 0) {
                #pragma unroll
                for (int nj = 0; nj < 4; ++nj)
                    #pragma unroll
                    for (int r = 0; r < 4; r++)
                        gbuf[(grow + r) * 68 + nj * 16 + gcol] += gacc[nj][r];
            }
            __syncthreads();
            {   // LSTM pointwise: thread -> (row rl, unit-pair q); c in registers
                const int rl = tid >> 3, q = tid & 7;
                const int b = gm0 + rl;
                const int npb = ng0 + q * 8;           // gate-slot base (2 units)
                const int u0 = npb >> 2;
                const int tb = text[b * STEPS + s];
                const float* gr = gbuf + rl * 68 + q * 8;
                float4 g0 = *(const float4*)gr;
                float4 g1 = *(const float4*)(gr + 4);
                float vi0 = g0.x + bias2r[npb + 0] + woh[(npb + 0) * NCLS + tb];
                float vf0 = g0.y + bias2r[npb + 1] + woh[(npb + 1) * NCLS + tb];
                float vg0 = g0.z + bias2r[npb + 2] + woh[(npb + 2) * NCLS + tb];
                float vo0 = g0.w + bias2r[npb + 3] + woh[(npb + 3) * NCLS + tb];
                float vi1 = g1.x + bias2r[npb + 4] + woh[(npb + 4) * NCLS + tb];
                float vf1 = g1.y + bias2r[npb + 5] + woh[(npb + 5) * NCLS + tb];
                float vg1 = g1.z + bias2r[npb + 6] + woh[(npb + 6) * NCLS + tb];
                float vo1 = g1.w + bias2r[npb + 7] + woh[(npb + 7) * NCLS + tb];
                float cn0 = sigmoid_f(vf0) * c0 + sigmoid_f(vi0) * tanh_f(vg0);
                float cn1 = sigmoid_f(vf1) * c1 + sigmoid_f(vi1) * tanh_f(vg1);
                c0 = cn0; c1 = cn1;
                float hn0 = sigmoid_f(vo0) * tanh_f(cn0);
                float hn1 = sigmoid_f(vo1) * tanh_f(cn1);
                unsigned hp2 = ((unsigned)f2bf(hn1) << 16) | (unsigned)f2bf(hn0);
                astore((unsigned*)(A2nxt + (size_t)b * 1024 + 512 + u0), hp2);  // coherent h
                *(unsigned*)(hseq + ((size_t)s * BATCH + b) * 512 + u0) = hp2;  // post-kernel only
            }
        }
        if (s + 1 < STEPS) gbar(gb, j, ++gen);
    }
}

// ---------------- host ----------------
extern "C" void kernel_launch(void* const* d_in, const int* in_sizes, int n_in,
                              void* d_out, int out_size, void* d_ws, size_t ws_size,
                              hipStream_t stream) {
    (void)in_sizes; (void)n_in; (void)out_size; (void)ws_size;
    const float* enc_f   = (const float*)d_in[0];
    const int*   text    = (const int*)d_in[1];
    const float* w_i2h   = (const float*)d_in[2];
    const float* w_h2h   = (const float*)d_in[3];
    const float* b_h2h   = (const float*)d_in[4];
    const float* w_score = (const float*)d_in[5];
    const float* w_ih    = (const float*)d_in[6];
    const float* w_hh    = (const float*)d_in[7];
    const float* b_ih    = (const float*)d_in[8];
    const float* b_hh    = (const float*)d_in[9];
    const float* w_gen   = (const float*)d_in[10];
    const float* b_gen   = (const float*)d_in[11];
    float* out = (float*)d_out;

    char* ws = (char*)d_ws;
    const unsigned short* Hp     = (const unsigned short*)(ws + HP_OFF);
    unsigned short*       Hp_w   = (unsigned short*)(ws + HP_OFF);
    const unsigned short* encb   = (const unsigned short*)(ws + ENC_OFF);
    unsigned short*       encb_w = (unsigned short*)(ws + ENC_OFF);
    unsigned short*       A2     = (unsigned short*)(ws + A2_OFF);
    float*                hpb    = (float*)(ws + HP32_OFF);
    const unsigned short* B2r    = (const unsigned short*)(ws + B2R_OFF);
    unsigned short*       B2r_w  = (unsigned short*)(ws + B2R_OFF);
    unsigned short*       wi2hb  = (unsigned short*)(ws + WI2H_OFF);
    const unsigned short* B3     = (const unsigned short*)(ws + B3_OFF);
    unsigned short*       B3_w   = (unsigned short*)(ws + B3_OFF);
    const float*          woh    = (const float*)(ws + WOH_OFF);
    float*                woh_w  = (float*)(ws + WOH_OFF);
    const float*          bias2r = (const float*)(ws + BIAS_OFF);
    float*                bias2r_w = (float*)(ws + BIAS_OFF);
    unsigned short*       hseq   = (unsigned short*)(ws + HSEQ_OFF);
    unsigned*             bar    = (unsigned*)(ws + BAR_OFF);

    conv_bf16_kernel<<<2048, 256, 0, stream>>>(enc_f, encb_w, BATCH * TENC * DIN / 4);
    conv_bf16_kernel<<<256, 256, 0, stream>>>(w_i2h, wi2hb, HDIM * DIN / 4);
    build_b2r_kernel<<<NG, 256, 0, stream>>>(w_ih, w_hh, b_ih, b_hh, B2r_w, woh_w, bias2r_w);
    build_b3_kernel<<<576, 256, 0, stream>>>(w_h2h, w_gen, B3_w);
    init_state_kernel<<<BATCH, 256, 0, stream>>>(A2, bar);

    // H_proj = enc @ w_i2h^T  (M=32768, N=512, K=512)
    gemm_bf16out_kernel<<<dim3(BATCH * TENC / 128, HDIM / 128), 256, 0, stream>>>(
        encb, DIN, wi2hb, DIN, Hp_w, HDIM, DIN);

    // cooperative decode: 8 independent 64-row groups, group-local barriers
    {
        void* args[13] = {
            (void*)&Hp, (void*)&encb, (void*)&A2, (void*)&hpb,
            (void*)&B2r, (void*)&bias2r, (void*)&woh, (void*)&B3,
            (void*)&b_h2h, (void*)&w_score, (void*)&text, (void*)&hseq, (void*)&bar
        };
        hipLaunchCooperativeKernel((const void*)decode_kernel, dim3(256), dim3(512),
                                   args, 0, stream);
    }

    // probs = hseq @ [w_gen;0]^T + b_gen  (M = S*B = 13312, N = 64, K = 512)
    probs_kernel<<<dim3(STEPS * BATCH / 64), 256, 0, stream>>>(
        hseq, B3 + (size_t)512 * 512, b_gen, out);
}